// Round 8
// baseline (3817.643 us; speedup 1.0000x reference)
//
#include <hip/hip_runtime.h>
#include <math.h>

// RationalQuadraticSpline: fused MLP (64->64->128->1600) + RQ spline.
// R7: fp32 numerics kept (MFMA bin-flip issue, R5). Structural attack:
//  - 512 thr (8 waves) x 64 rows, 2 rows/thread -> 2 blocks/CU = 16 waves/CU
//  - W3 pre-packed (pad 25->28) in d_ws so slab staging is LDS-linear ->
//    global_load_lds width-16 DMA staging (zero staging VALU/VGPR)
//  - single barrier per k-slab, DMA prefetch hidden under FMA/spline
//  - __launch_bounds__(512,4) caps VGPR at 128 for 4 waves/SIMD

namespace {

constexpr int NTHR = 512;
constexpr int ROWS = 64;
constexpr float TBOUND = 3.0f;

typedef __attribute__((ext_vector_type(4))) float f32x4v;

__device__ inline void g2l16(const float* g, float* l) {
  __builtin_amdgcn_global_load_lds(
      (const __attribute__((address_space(1))) unsigned int*)g,
      (__attribute__((address_space(3))) unsigned int*)l, 16, 0, 0);
}

// ---- pack W3 [128][1600] -> W3p [128][1792]: col f*25+p -> f*28+p ----
__global__ __launch_bounds__(256) void pack_w3(const float* __restrict__ W3,
                                               float* __restrict__ W3p) {
  int idx = blockIdx.x * 256 + threadIdx.x;   // 204800
  int k = idx / 1600;
  int c = idx - k * 1600;
  int fg = c / 25;
  int p = c - fg * 25;
  W3p[(size_t)k * 1792 + fg * 28 + p] = W3[idx];
}

__global__ __launch_bounds__(NTHR, 4) void rqs_fused(
    const float* __restrict__ x, const float* __restrict__ W1,
    const float* __restrict__ b1, const float* __restrict__ W2,
    const float* __restrict__ b2, const float* __restrict__ W3p,
    const float* __restrict__ b3, float* __restrict__ out,
    float* __restrict__ ldet) {
  __shared__ float xs[ROWS][68];     // x in; y written in-place
  __shared__ float h2s[ROWS][132];
  __shared__ float uni[7168];        // GEMM1/2: h1s[64][68]; GEMM3: slab[2][8][448]

  const int t = threadIdx.x;
  const int row0 = blockIdx.x * ROWS;

  for (int i = t; i < ROWS * 64; i += NTHR) {
    int r = i >> 6, c = i & 63;
    xs[r][c] = x[(size_t)(row0 + r) * 64 + c];
  }
  __syncthreads();

  // ---- GEMM1: h1 = relu(x @ W1 + b1); 1 col x 8 rows/thread ----
  {
    const int c = t & 63;
    const int rg = (t >> 6) * 8;
    float acc[8];
#pragma unroll
    for (int j = 0; j < 8; ++j) acc[j] = 0.f;
    for (int k4 = 0; k4 < 16; ++k4) {
      float w0 = W1[(k4 * 4 + 0) * 64 + c];
      float w1 = W1[(k4 * 4 + 1) * 64 + c];
      float w2 = W1[(k4 * 4 + 2) * 64 + c];
      float w3v = W1[(k4 * 4 + 3) * 64 + c];
#pragma unroll
      for (int j = 0; j < 8; ++j) {
        f32x4v xv = *(const f32x4v*)&xs[rg + j][k4 * 4];
        acc[j] = fmaf(xv[0], w0, acc[j]);
        acc[j] = fmaf(xv[1], w1, acc[j]);
        acc[j] = fmaf(xv[2], w2, acc[j]);
        acc[j] = fmaf(xv[3], w3v, acc[j]);
      }
    }
    float bb = b1[c];
#pragma unroll
    for (int j = 0; j < 8; ++j)
      uni[(rg + j) * 68 + c] = fmaxf(acc[j] + bb, 0.f);
  }
  __syncthreads();

  // ---- GEMM2: h2 = relu(h1 @ W2 + b2); 2 cols x 8 rows/thread ----
  {
    const int c2 = t & 63;
    const int rg = (t >> 6) * 8;
    float a0[8], a1[8];
#pragma unroll
    for (int j = 0; j < 8; ++j) { a0[j] = 0.f; a1[j] = 0.f; }
    for (int k4 = 0; k4 < 16; ++k4) {
      float w00 = W2[(k4 * 4 + 0) * 128 + c2], w10 = W2[(k4 * 4 + 0) * 128 + c2 + 64];
      float w01 = W2[(k4 * 4 + 1) * 128 + c2], w11 = W2[(k4 * 4 + 1) * 128 + c2 + 64];
      float w02 = W2[(k4 * 4 + 2) * 128 + c2], w12 = W2[(k4 * 4 + 2) * 128 + c2 + 64];
      float w03 = W2[(k4 * 4 + 3) * 128 + c2], w13 = W2[(k4 * 4 + 3) * 128 + c2 + 64];
#pragma unroll
      for (int j = 0; j < 8; ++j) {
        f32x4v hv = *(const f32x4v*)&uni[(rg + j) * 68 + k4 * 4];
        a0[j] = fmaf(hv[0], w00, a0[j]);
        a0[j] = fmaf(hv[1], w01, a0[j]);
        a0[j] = fmaf(hv[2], w02, a0[j]);
        a0[j] = fmaf(hv[3], w03, a0[j]);
        a1[j] = fmaf(hv[0], w10, a1[j]);
        a1[j] = fmaf(hv[1], w11, a1[j]);
        a1[j] = fmaf(hv[2], w12, a1[j]);
        a1[j] = fmaf(hv[3], w13, a1[j]);
      }
    }
    float bb0 = b2[c2], bb1 = b2[c2 + 64];
#pragma unroll
    for (int j = 0; j < 8; ++j) {
      h2s[rg + j][c2] = fmaxf(a0[j] + bb0, 0.f);
      h2s[rg + j][c2 + 64] = fmaxf(a1[j] + bb1, 0.f);
    }
  }
  __syncthreads();   // h1s dead; uni becomes slab double-buffer

  // ---- GEMM3 + spline: thread = (rgrp in [0,32) -> 2 rows, f in [0,16)) ----
  const int f = t & 15;
  const int rgrp = t >> 4;

  // DMA staging geometry: per k-slab = 8 rows x 448 floats = 896 x 16B chunks.
  // chunk c0 = t (all 512), c1 = 512+t (waves 0..5, t<384: wave-uniform guard)
  const int kk0 = t / 112, col0 = t - kk0 * 112;
  const int c1 = 512 + t;
  const int kk1 = c1 / 112, col1 = c1 - kk1 * 112;

#define ISSUE_SLAB(CH, KS, SB)                                                \
  do {                                                                        \
    const float* wsrc = W3p + (size_t)(KS)*14336 + (CH)*448;                  \
    g2l16(wsrc + kk0 * 1792 + col0 * 4, &uni[(SB) + t * 4]);                  \
    if (t < 384) g2l16(wsrc + kk1 * 1792 + col1 * 4, &uni[(SB) + c1 * 4]);    \
  } while (0)

  float ldacc[2] = {0.f, 0.f};
  float acc[2][25];

  ISSUE_SLAB(0, 0, 0);

#pragma unroll 1
  for (int s = 0; s < 64; ++s) {
    const int ch = s >> 4, ks = s & 15;
    const int sb = (s & 1) * 3584;
    __syncthreads();                 // slab[sb] loads landed; prev readers done
    if (s < 63) {
      const int sn = s + 1;
      ISSUE_SLAB(sn >> 4, sn & 15, (sn & 1) * 3584);
    }

    if (ks == 0) {
#pragma unroll
      for (int j = 0; j < 2; ++j)
#pragma unroll
        for (int p = 0; p < 25; ++p) acc[j][p] = 0.f;
    }

#pragma unroll
    for (int kq = 0; kq < 2; ++kq) {
      f32x4v ha0 = *(const f32x4v*)&h2s[rgrp * 2 + 0][ks * 8 + kq * 4];
      f32x4v ha1 = *(const f32x4v*)&h2s[rgrp * 2 + 1][ks * 8 + kq * 4];
#pragma unroll
      for (int e = 0; e < 4; ++e) {
        f32x4v w4[7];
#pragma unroll
        for (int q7 = 0; q7 < 7; ++q7)
          w4[q7] = *(const f32x4v*)&uni[sb + (kq * 4 + e) * 448 + f * 28 + q7 * 4];
#pragma unroll
        for (int p = 0; p < 25; ++p) {
          float wv = w4[p >> 2][p & 3];
          acc[0][p] = fmaf(ha0[e], wv, acc[0][p]);
          acc[1][p] = fmaf(ha1[e], wv, acc[1][p]);
        }
      }
    }

    if (ks == 15) {
      // ---- bias + spline for this thread's 2 rows, from registers ----
      float b3v[25];
#pragma unroll
      for (int p = 0; p < 25; ++p) b3v[p] = b3[ch * 400 + f * 25 + p];
#pragma unroll
      for (int j = 0; j < 2; ++j) {
        const int r = rgrp * 2 + j;
        float pp[25];
#pragma unroll
        for (int p = 0; p < 25; ++p) pp[p] = acc[j][p] + b3v[p];
        const float xv = xs[r][ch * 16 + f];

        float we[8], hh[8], dd[9];
        float m = pp[0];
#pragma unroll
        for (int q = 1; q < 8; ++q) m = fmaxf(m, pp[q]);
        float sum = 0.f;
#pragma unroll
        for (int q = 0; q < 8; ++q) { we[q] = __expf(pp[q] - m); sum += we[q]; }
        float sc = 5.952f / sum;
#pragma unroll
        for (int q = 0; q < 8; ++q) we[q] = we[q] * sc + 0.001f;
        m = pp[8];
#pragma unroll
        for (int q = 1; q < 8; ++q) m = fmaxf(m, pp[8 + q]);
        sum = 0.f;
#pragma unroll
        for (int q = 0; q < 8; ++q) { hh[q] = __expf(pp[8 + q] - m); sum += hh[q]; }
        sc = 5.952f / sum;
#pragma unroll
        for (int q = 0; q < 8; ++q) hh[q] = hh[q] * sc + 0.001f;
#pragma unroll
        for (int q = 0; q < 9; ++q) {
          float v = pp[16 + q];
          dd[q] = fmaxf(v, 0.f) + __logf(1.f + __expf(-fabsf(v))) + 0.001f;
        }

        const bool inside = (xv >= -TBOUND) && (xv <= TBOUND);
        const float xc = fminf(fmaxf(xv, -TBOUND), TBOUND);

        float cw = -TBOUND + we[0];
        float chh = -TBOUND + hh[0];
        float cwk = -TBOUND, chk = -TBOUND;
        float wk = we[0], hk = hh[0], dk = dd[0], dk1 = dd[1];
#pragma unroll
        for (int q = 1; q < 8; ++q) {
          bool g = (cw <= xc);
          cwk = g ? cw : cwk;
          chk = g ? chh : chk;
          wk = g ? we[q] : wk;
          hk = g ? hh[q] : hk;
          dk = g ? dd[q] : dk;
          dk1 = g ? dd[q + 1] : dk1;
          cw += we[q];
          chh += hh[q];
        }

        float th = (xc - cwk) / wk;
        float om = 1.f - th;
        float th2 = th * th, thom = th * om, om2 = om * om;
        float num = hk * (dk * th2 + dk1 * thom);
        float den = dk * th2 + 2.f * dk1 * thom + dk1 * om2;
        float yv = chk + num / den;
        float dn = dk1 * th2 + 2.f * dk * thom + dk * om2;
        float ld = 2.f * __logf(dn) - 2.f * __logf(den) + __logf(hk) - __logf(wk);

        xs[r][ch * 16 + f] = inside ? yv : xv;   // y in-place (own slot)
        ldacc[j] += inside ? ld : 0.f;
      }
    }
  }

  // ---- ldet: butterfly reduce over the 16 f-lanes (same wave) ----
#pragma unroll
  for (int j = 0; j < 2; ++j) {
    float v = ldacc[j];
    v += __shfl_xor(v, 1);
    v += __shfl_xor(v, 2);
    v += __shfl_xor(v, 4);
    v += __shfl_xor(v, 8);
    if (f == 0) ldet[row0 + rgrp * 2 + j] = v;
  }
  __syncthreads();

  // ---- epilogue: coalesced y writes ----
  for (int i = t; i < ROWS * 64; i += NTHR) {
    int r = i >> 6, c = i & 63;
    out[(size_t)(row0 + r) * 64 + c] = xs[r][c];
  }
#undef ISSUE_SLAB
}

}  // namespace

extern "C" void kernel_launch(void* const* d_in, const int* in_sizes, int n_in,
                              void* d_out, int out_size, void* d_ws, size_t ws_size,
                              hipStream_t stream) {
  const float* x = (const float*)d_in[0];
  const float* W1 = (const float*)d_in[1];
  const float* b1 = (const float*)d_in[2];
  const float* W2 = (const float*)d_in[3];
  const float* b2 = (const float*)d_in[4];
  const float* W3 = (const float*)d_in[5];
  const float* b3 = (const float*)d_in[6];
  float* out = (float*)d_out;
  float* ldet = out + (size_t)65536 * 64;
  float* W3p = (float*)d_ws;   // 128*1792*4 = 917504 B

  pack_w3<<<dim3(800), dim3(256), 0, stream>>>(W3, W3p);
  rqs_fused<<<dim3(65536 / ROWS), dim3(NTHR), 0, stream>>>(
      x, W1, b1, W2, b2, W3p, b3, out, ldet);
}

// Round 9
// 3472.673 us; speedup vs baseline: 1.0993x; 1.0993x over previous
//
#include <hip/hip_runtime.h>
#include <math.h>

// RationalQuadraticSpline: fused MLP (64->64->128->1600) + RQ spline.
// R8: R7 structure (512 thr / 64 rows / DMA slab staging / 16 waves/CU) with
// the spill fixed: spline runs IN PLACE on acc[j] (bias folded, we/hh/dd
// overwrite acc slots) so peak VGPR ~75 < 128 cap. R7 spilled acc -> 11 GB
// scratch traffic -> HBM-bound at 4-12% VALU.

namespace {

constexpr int NTHR = 512;
constexpr int ROWS = 64;
constexpr float TBOUND = 3.0f;

typedef __attribute__((ext_vector_type(4))) float f32x4v;

__device__ inline void g2l16(const float* g, float* l) {
  __builtin_amdgcn_global_load_lds(
      (const __attribute__((address_space(1))) unsigned int*)g,
      (__attribute__((address_space(3))) unsigned int*)l, 16, 0, 0);
}

// ---- pack W3 [128][1600] -> W3p [128][1792]: col f*25+p -> f*28+p ----
__global__ __launch_bounds__(256) void pack_w3(const float* __restrict__ W3,
                                               float* __restrict__ W3p) {
  int idx = blockIdx.x * 256 + threadIdx.x;   // 204800
  int k = idx / 1600;
  int c = idx - k * 1600;
  int fg = c / 25;
  int p = c - fg * 25;
  W3p[(size_t)k * 1792 + fg * 28 + p] = W3[idx];
}

__global__ __launch_bounds__(NTHR, 4) void rqs_fused(
    const float* __restrict__ x, const float* __restrict__ W1,
    const float* __restrict__ b1, const float* __restrict__ W2,
    const float* __restrict__ b2, const float* __restrict__ W3p,
    const float* __restrict__ b3, float* __restrict__ out,
    float* __restrict__ ldet) {
  __shared__ float xs[ROWS][68];     // x in; y written in-place
  __shared__ float h2s[ROWS][132];
  __shared__ float uni[7168];        // GEMM1/2: h1s[64][68]; GEMM3: slab[2][8][448]

  const int t = threadIdx.x;
  const int row0 = blockIdx.x * ROWS;

  for (int i = t; i < ROWS * 64; i += NTHR) {
    int r = i >> 6, c = i & 63;
    xs[r][c] = x[(size_t)(row0 + r) * 64 + c];
  }
  __syncthreads();

  // ---- GEMM1: h1 = relu(x @ W1 + b1); 1 col x 8 rows/thread ----
  {
    const int c = t & 63;
    const int rg = (t >> 6) * 8;
    float acc1[8];
#pragma unroll
    for (int j = 0; j < 8; ++j) acc1[j] = 0.f;
    for (int k4 = 0; k4 < 16; ++k4) {
      float w0 = W1[(k4 * 4 + 0) * 64 + c];
      float w1 = W1[(k4 * 4 + 1) * 64 + c];
      float w2 = W1[(k4 * 4 + 2) * 64 + c];
      float w3v = W1[(k4 * 4 + 3) * 64 + c];
#pragma unroll
      for (int j = 0; j < 8; ++j) {
        f32x4v xv = *(const f32x4v*)&xs[rg + j][k4 * 4];
        acc1[j] = fmaf(xv[0], w0, acc1[j]);
        acc1[j] = fmaf(xv[1], w1, acc1[j]);
        acc1[j] = fmaf(xv[2], w2, acc1[j]);
        acc1[j] = fmaf(xv[3], w3v, acc1[j]);
      }
    }
    float bb = b1[c];
#pragma unroll
    for (int j = 0; j < 8; ++j)
      uni[(rg + j) * 68 + c] = fmaxf(acc1[j] + bb, 0.f);
  }
  __syncthreads();

  // ---- GEMM2: h2 = relu(h1 @ W2 + b2); 2 cols x 8 rows/thread ----
  {
    const int c2 = t & 63;
    const int rg = (t >> 6) * 8;
    float a0[8], a1[8];
#pragma unroll
    for (int j = 0; j < 8; ++j) { a0[j] = 0.f; a1[j] = 0.f; }
    for (int k4 = 0; k4 < 16; ++k4) {
      float w00 = W2[(k4 * 4 + 0) * 128 + c2], w10 = W2[(k4 * 4 + 0) * 128 + c2 + 64];
      float w01 = W2[(k4 * 4 + 1) * 128 + c2], w11 = W2[(k4 * 4 + 1) * 128 + c2 + 64];
      float w02 = W2[(k4 * 4 + 2) * 128 + c2], w12 = W2[(k4 * 4 + 2) * 128 + c2 + 64];
      float w03 = W2[(k4 * 4 + 3) * 128 + c2], w13 = W2[(k4 * 4 + 3) * 128 + c2 + 64];
#pragma unroll
      for (int j = 0; j < 8; ++j) {
        f32x4v hv = *(const f32x4v*)&uni[(rg + j) * 68 + k4 * 4];
        a0[j] = fmaf(hv[0], w00, a0[j]);
        a0[j] = fmaf(hv[1], w01, a0[j]);
        a0[j] = fmaf(hv[2], w02, a0[j]);
        a0[j] = fmaf(hv[3], w03, a0[j]);
        a1[j] = fmaf(hv[0], w10, a1[j]);
        a1[j] = fmaf(hv[1], w11, a1[j]);
        a1[j] = fmaf(hv[2], w12, a1[j]);
        a1[j] = fmaf(hv[3], w13, a1[j]);
      }
    }
    float bb0 = b2[c2], bb1 = b2[c2 + 64];
#pragma unroll
    for (int j = 0; j < 8; ++j) {
      h2s[rg + j][c2] = fmaxf(a0[j] + bb0, 0.f);
      h2s[rg + j][c2 + 64] = fmaxf(a1[j] + bb1, 0.f);
    }
  }
  __syncthreads();   // h1s dead; uni becomes slab double-buffer

  // ---- GEMM3 + spline: thread = (rgrp in [0,32) -> 2 rows, f in [0,16)) ----
  const int f = t & 15;
  const int rgrp = t >> 4;

  // DMA staging geometry: per k-slab = 8 rows x 448 floats = 896 x 16B chunks.
  const int kk0 = t / 112, col0 = t - kk0 * 112;
  const int c1 = 512 + t;
  const int kk1 = c1 / 112, col1 = c1 - kk1 * 112;

#define ISSUE_SLAB(CH, KS, SB)                                                \
  do {                                                                        \
    const float* wsrc = W3p + (size_t)(KS)*14336 + (CH)*448;                  \
    g2l16(wsrc + kk0 * 1792 + col0 * 4, &uni[(SB) + t * 4]);                  \
    if (t < 384) g2l16(wsrc + kk1 * 1792 + col1 * 4, &uni[(SB) + c1 * 4]);    \
  } while (0)

  float ldacc[2] = {0.f, 0.f};
  float acc[2][25];

  ISSUE_SLAB(0, 0, 0);

#pragma unroll 1
  for (int s = 0; s < 64; ++s) {
    const int ch = s >> 4, ks = s & 15;
    const int sb = (s & 1) * 3584;
    __syncthreads();                 // slab[sb] loads landed; prev readers done
    if (s < 63) {
      const int sn = s + 1;
      ISSUE_SLAB(sn >> 4, sn & 15, (sn & 1) * 3584);
    }

    if (ks == 0) {
#pragma unroll
      for (int j = 0; j < 2; ++j)
#pragma unroll
        for (int p = 0; p < 25; ++p) acc[j][p] = 0.f;
    }

#pragma unroll
    for (int kq = 0; kq < 2; ++kq) {
      f32x4v ha0 = *(const f32x4v*)&h2s[rgrp * 2 + 0][ks * 8 + kq * 4];
      f32x4v ha1 = *(const f32x4v*)&h2s[rgrp * 2 + 1][ks * 8 + kq * 4];
#pragma unroll
      for (int e = 0; e < 4; ++e) {
        f32x4v w4[7];
#pragma unroll
        for (int q7 = 0; q7 < 7; ++q7)
          w4[q7] = *(const f32x4v*)&uni[sb + (kq * 4 + e) * 448 + f * 28 + q7 * 4];
#pragma unroll
        for (int p = 0; p < 25; ++p) {
          float wv = w4[p >> 2][p & 3];
          acc[0][p] = fmaf(ha0[e], wv, acc[0][p]);
          acc[1][p] = fmaf(ha1[e], wv, acc[1][p]);
        }
      }
    }

    if (ks == 15) {
      // ---- spline IN PLACE on acc[j] (bias folded; we/hh/dd overwrite acc) ----
      const float* b3p = b3 + ch * 400 + f * 25;
#pragma unroll
      for (int j = 0; j < 2; ++j) {
        const int r = rgrp * 2 + j;
#pragma unroll
        for (int p = 0; p < 25; ++p) acc[j][p] += b3p[p];   // params done
        const float xv = xs[r][ch * 16 + f];

        // widths -> acc[j][0..8)
        float m = acc[j][0];
#pragma unroll
        for (int q = 1; q < 8; ++q) m = fmaxf(m, acc[j][q]);
        float sum = 0.f;
#pragma unroll
        for (int q = 0; q < 8; ++q) { acc[j][q] = __expf(acc[j][q] - m); sum += acc[j][q]; }
        float sc = 5.952f / sum;
#pragma unroll
        for (int q = 0; q < 8; ++q) acc[j][q] = acc[j][q] * sc + 0.001f;
        // heights -> acc[j][8..16)
        m = acc[j][8];
#pragma unroll
        for (int q = 1; q < 8; ++q) m = fmaxf(m, acc[j][8 + q]);
        sum = 0.f;
#pragma unroll
        for (int q = 0; q < 8; ++q) { acc[j][8 + q] = __expf(acc[j][8 + q] - m); sum += acc[j][8 + q]; }
        sc = 5.952f / sum;
#pragma unroll
        for (int q = 0; q < 8; ++q) acc[j][8 + q] = acc[j][8 + q] * sc + 0.001f;
        // derivs -> acc[j][16..25)
#pragma unroll
        for (int q = 0; q < 9; ++q) {
          float v = acc[j][16 + q];
          acc[j][16 + q] = fmaxf(v, 0.f) + __logf(1.f + __expf(-fabsf(v))) + 0.001f;
        }

        const bool inside = (xv >= -TBOUND) && (xv <= TBOUND);
        const float xc = fminf(fmaxf(xv, -TBOUND), TBOUND);

        float cw = -TBOUND + acc[j][0];
        float chh = -TBOUND + acc[j][8];
        float cwk = -TBOUND, chk = -TBOUND;
        float wk = acc[j][0], hk = acc[j][8], dk = acc[j][16], dk1 = acc[j][17];
#pragma unroll
        for (int q = 1; q < 8; ++q) {
          bool g = (cw <= xc);
          cwk = g ? cw : cwk;
          chk = g ? chh : chk;
          wk = g ? acc[j][q] : wk;
          hk = g ? acc[j][8 + q] : hk;
          dk = g ? acc[j][16 + q] : dk;
          dk1 = g ? acc[j][17 + q] : dk1;
          cw += acc[j][q];
          chh += acc[j][8 + q];
        }

        float th = (xc - cwk) / wk;
        float om = 1.f - th;
        float th2 = th * th, thom = th * om, om2 = om * om;
        float num = hk * (dk * th2 + dk1 * thom);
        float den = dk * th2 + 2.f * dk1 * thom + dk1 * om2;
        float yv = chk + num / den;
        float dn = dk1 * th2 + 2.f * dk * thom + dk * om2;
        float ld = 2.f * __logf(dn) - 2.f * __logf(den) + __logf(hk) - __logf(wk);

        xs[r][ch * 16 + f] = inside ? yv : xv;   // y in-place (own slot)
        ldacc[j] += inside ? ld : 0.f;
      }
    }
  }

  // ---- ldet: butterfly reduce over the 16 f-lanes (same wave) ----
#pragma unroll
  for (int j = 0; j < 2; ++j) {
    float v = ldacc[j];
    v += __shfl_xor(v, 1);
    v += __shfl_xor(v, 2);
    v += __shfl_xor(v, 4);
    v += __shfl_xor(v, 8);
    if (f == 0) ldet[row0 + rgrp * 2 + j] = v;
  }
  __syncthreads();

  // ---- epilogue: coalesced y writes ----
  for (int i = t; i < ROWS * 64; i += NTHR) {
    int r = i >> 6, c = i & 63;
    out[(size_t)(row0 + r) * 64 + c] = xs[r][c];
  }
#undef ISSUE_SLAB
}

}  // namespace

extern "C" void kernel_launch(void* const* d_in, const int* in_sizes, int n_in,
                              void* d_out, int out_size, void* d_ws, size_t ws_size,
                              hipStream_t stream) {
  const float* x = (const float*)d_in[0];
  const float* W1 = (const float*)d_in[1];
  const float* b1 = (const float*)d_in[2];
  const float* W2 = (const float*)d_in[3];
  const float* b2 = (const float*)d_in[4];
  const float* W3 = (const float*)d_in[5];
  const float* b3 = (const float*)d_in[6];
  float* out = (float*)d_out;
  float* ldet = out + (size_t)65536 * 64;
  float* W3p = (float*)d_ws;   // 128*1792*4 = 917504 B

  pack_w3<<<dim3(800), dim3(256), 0, stream>>>(W3, W3p);
  rqs_fused<<<dim3(65536 / ROWS), dim3(NTHR), 0, stream>>>(
      x, W1, b1, W2, b2, W3p, b3, out, ldet);
}

// Round 10
// 605.765 us; speedup vs baseline: 6.3022x; 5.7327x over previous
//
#include <hip/hip_runtime.h>
#include <math.h>

// RationalQuadraticSpline: fused MLP (64->64->128->1600) + RQ spline.
// R9: identical to R8 except __launch_bounds__(512, 2). R8's (512,4) was
// interpreted as 4 BLOCKS/CU (CUDA semantics) -> 8 waves/SIMD -> 64-VGPR cap
// -> acc[2][25] spilled -> 10 GB scratch traffic. (512,2) -> 2 blocks/CU
// (= the LDS limit) -> 4 waves/SIMD -> 128-VGPR cap -> no spill.

namespace {

constexpr int NTHR = 512;
constexpr int ROWS = 64;
constexpr float TBOUND = 3.0f;

typedef __attribute__((ext_vector_type(4))) float f32x4v;

__device__ inline void g2l16(const float* g, float* l) {
  __builtin_amdgcn_global_load_lds(
      (const __attribute__((address_space(1))) unsigned int*)g,
      (__attribute__((address_space(3))) unsigned int*)l, 16, 0, 0);
}

// ---- pack W3 [128][1600] -> W3p [128][1792]: col f*25+p -> f*28+p ----
__global__ __launch_bounds__(256) void pack_w3(const float* __restrict__ W3,
                                               float* __restrict__ W3p) {
  int idx = blockIdx.x * 256 + threadIdx.x;   // 204800
  int k = idx / 1600;
  int c = idx - k * 1600;
  int fg = c / 25;
  int p = c - fg * 25;
  W3p[(size_t)k * 1792 + fg * 28 + p] = W3[idx];
}

__global__ __launch_bounds__(NTHR, 2) void rqs_fused(
    const float* __restrict__ x, const float* __restrict__ W1,
    const float* __restrict__ b1, const float* __restrict__ W2,
    const float* __restrict__ b2, const float* __restrict__ W3p,
    const float* __restrict__ b3, float* __restrict__ out,
    float* __restrict__ ldet) {
  __shared__ float xs[ROWS][68];     // x in; y written in-place
  __shared__ float h2s[ROWS][132];
  __shared__ float uni[7168];        // GEMM1/2: h1s[64][68]; GEMM3: slab[2][8][448]

  const int t = threadIdx.x;
  const int row0 = blockIdx.x * ROWS;

  for (int i = t; i < ROWS * 64; i += NTHR) {
    int r = i >> 6, c = i & 63;
    xs[r][c] = x[(size_t)(row0 + r) * 64 + c];
  }
  __syncthreads();

  // ---- GEMM1: h1 = relu(x @ W1 + b1); 1 col x 8 rows/thread ----
  {
    const int c = t & 63;
    const int rg = (t >> 6) * 8;
    float acc1[8];
#pragma unroll
    for (int j = 0; j < 8; ++j) acc1[j] = 0.f;
    for (int k4 = 0; k4 < 16; ++k4) {
      float w0 = W1[(k4 * 4 + 0) * 64 + c];
      float w1 = W1[(k4 * 4 + 1) * 64 + c];
      float w2 = W1[(k4 * 4 + 2) * 64 + c];
      float w3v = W1[(k4 * 4 + 3) * 64 + c];
#pragma unroll
      for (int j = 0; j < 8; ++j) {
        f32x4v xv = *(const f32x4v*)&xs[rg + j][k4 * 4];
        acc1[j] = fmaf(xv[0], w0, acc1[j]);
        acc1[j] = fmaf(xv[1], w1, acc1[j]);
        acc1[j] = fmaf(xv[2], w2, acc1[j]);
        acc1[j] = fmaf(xv[3], w3v, acc1[j]);
      }
    }
    float bb = b1[c];
#pragma unroll
    for (int j = 0; j < 8; ++j)
      uni[(rg + j) * 68 + c] = fmaxf(acc1[j] + bb, 0.f);
  }
  __syncthreads();

  // ---- GEMM2: h2 = relu(h1 @ W2 + b2); 2 cols x 8 rows/thread ----
  {
    const int c2 = t & 63;
    const int rg = (t >> 6) * 8;
    float a0[8], a1[8];
#pragma unroll
    for (int j = 0; j < 8; ++j) { a0[j] = 0.f; a1[j] = 0.f; }
    for (int k4 = 0; k4 < 16; ++k4) {
      float w00 = W2[(k4 * 4 + 0) * 128 + c2], w10 = W2[(k4 * 4 + 0) * 128 + c2 + 64];
      float w01 = W2[(k4 * 4 + 1) * 128 + c2], w11 = W2[(k4 * 4 + 1) * 128 + c2 + 64];
      float w02 = W2[(k4 * 4 + 2) * 128 + c2], w12 = W2[(k4 * 4 + 2) * 128 + c2 + 64];
      float w03 = W2[(k4 * 4 + 3) * 128 + c2], w13 = W2[(k4 * 4 + 3) * 128 + c2 + 64];
#pragma unroll
      for (int j = 0; j < 8; ++j) {
        f32x4v hv = *(const f32x4v*)&uni[(rg + j) * 68 + k4 * 4];
        a0[j] = fmaf(hv[0], w00, a0[j]);
        a0[j] = fmaf(hv[1], w01, a0[j]);
        a0[j] = fmaf(hv[2], w02, a0[j]);
        a0[j] = fmaf(hv[3], w03, a0[j]);
        a1[j] = fmaf(hv[0], w10, a1[j]);
        a1[j] = fmaf(hv[1], w11, a1[j]);
        a1[j] = fmaf(hv[2], w12, a1[j]);
        a1[j] = fmaf(hv[3], w13, a1[j]);
      }
    }
    float bb0 = b2[c2], bb1 = b2[c2 + 64];
#pragma unroll
    for (int j = 0; j < 8; ++j) {
      h2s[rg + j][c2] = fmaxf(a0[j] + bb0, 0.f);
      h2s[rg + j][c2 + 64] = fmaxf(a1[j] + bb1, 0.f);
    }
  }
  __syncthreads();   // h1s dead; uni becomes slab double-buffer

  // ---- GEMM3 + spline: thread = (rgrp in [0,32) -> 2 rows, f in [0,16)) ----
  const int f = t & 15;
  const int rgrp = t >> 4;

  // DMA staging geometry: per k-slab = 8 rows x 448 floats = 896 x 16B chunks.
  const int kk0 = t / 112, col0 = t - kk0 * 112;
  const int c1 = 512 + t;
  const int kk1 = c1 / 112, col1 = c1 - kk1 * 112;

#define ISSUE_SLAB(CH, KS, SB)                                                \
  do {                                                                        \
    const float* wsrc = W3p + (size_t)(KS)*14336 + (CH)*448;                  \
    g2l16(wsrc + kk0 * 1792 + col0 * 4, &uni[(SB) + t * 4]);                  \
    if (t < 384) g2l16(wsrc + kk1 * 1792 + col1 * 4, &uni[(SB) + c1 * 4]);    \
  } while (0)

  float ldacc[2] = {0.f, 0.f};
  float acc[2][25];

  ISSUE_SLAB(0, 0, 0);

#pragma unroll 1
  for (int s = 0; s < 64; ++s) {
    const int ch = s >> 4, ks = s & 15;
    const int sb = (s & 1) * 3584;
    __syncthreads();                 // slab[sb] loads landed; prev readers done
    if (s < 63) {
      const int sn = s + 1;
      ISSUE_SLAB(sn >> 4, sn & 15, (sn & 1) * 3584);
    }

    if (ks == 0) {
#pragma unroll
      for (int j = 0; j < 2; ++j)
#pragma unroll
        for (int p = 0; p < 25; ++p) acc[j][p] = 0.f;
    }

#pragma unroll
    for (int kq = 0; kq < 2; ++kq) {
      f32x4v ha0 = *(const f32x4v*)&h2s[rgrp * 2 + 0][ks * 8 + kq * 4];
      f32x4v ha1 = *(const f32x4v*)&h2s[rgrp * 2 + 1][ks * 8 + kq * 4];
#pragma unroll
      for (int e = 0; e < 4; ++e) {
        f32x4v w4[7];
#pragma unroll
        for (int q7 = 0; q7 < 7; ++q7)
          w4[q7] = *(const f32x4v*)&uni[sb + (kq * 4 + e) * 448 + f * 28 + q7 * 4];
#pragma unroll
        for (int p = 0; p < 25; ++p) {
          float wv = w4[p >> 2][p & 3];
          acc[0][p] = fmaf(ha0[e], wv, acc[0][p]);
          acc[1][p] = fmaf(ha1[e], wv, acc[1][p]);
        }
      }
    }

    if (ks == 15) {
      // ---- spline IN PLACE on acc[j] (bias folded; we/hh/dd overwrite acc) ----
      const float* b3p = b3 + ch * 400 + f * 25;
#pragma unroll
      for (int j = 0; j < 2; ++j) {
        const int r = rgrp * 2 + j;
#pragma unroll
        for (int p = 0; p < 25; ++p) acc[j][p] += b3p[p];   // params done
        const float xv = xs[r][ch * 16 + f];

        // widths -> acc[j][0..8)
        float m = acc[j][0];
#pragma unroll
        for (int q = 1; q < 8; ++q) m = fmaxf(m, acc[j][q]);
        float sum = 0.f;
#pragma unroll
        for (int q = 0; q < 8; ++q) { acc[j][q] = __expf(acc[j][q] - m); sum += acc[j][q]; }
        float sc = 5.952f / sum;
#pragma unroll
        for (int q = 0; q < 8; ++q) acc[j][q] = acc[j][q] * sc + 0.001f;
        // heights -> acc[j][8..16)
        m = acc[j][8];
#pragma unroll
        for (int q = 1; q < 8; ++q) m = fmaxf(m, acc[j][8 + q]);
        sum = 0.f;
#pragma unroll
        for (int q = 0; q < 8; ++q) { acc[j][8 + q] = __expf(acc[j][8 + q] - m); sum += acc[j][8 + q]; }
        sc = 5.952f / sum;
#pragma unroll
        for (int q = 0; q < 8; ++q) acc[j][8 + q] = acc[j][8 + q] * sc + 0.001f;
        // derivs -> acc[j][16..25)
#pragma unroll
        for (int q = 0; q < 9; ++q) {
          float v = acc[j][16 + q];
          acc[j][16 + q] = fmaxf(v, 0.f) + __logf(1.f + __expf(-fabsf(v))) + 0.001f;
        }

        const bool inside = (xv >= -TBOUND) && (xv <= TBOUND);
        const float xc = fminf(fmaxf(xv, -TBOUND), TBOUND);

        float cw = -TBOUND + acc[j][0];
        float chh = -TBOUND + acc[j][8];
        float cwk = -TBOUND, chk = -TBOUND;
        float wk = acc[j][0], hk = acc[j][8], dk = acc[j][16], dk1 = acc[j][17];
#pragma unroll
        for (int q = 1; q < 8; ++q) {
          bool g = (cw <= xc);
          cwk = g ? cw : cwk;
          chk = g ? chh : chk;
          wk = g ? acc[j][q] : wk;
          hk = g ? acc[j][8 + q] : hk;
          dk = g ? acc[j][16 + q] : dk;
          dk1 = g ? acc[j][17 + q] : dk1;
          cw += acc[j][q];
          chh += acc[j][8 + q];
        }

        float th = (xc - cwk) / wk;
        float om = 1.f - th;
        float th2 = th * th, thom = th * om, om2 = om * om;
        float num = hk * (dk * th2 + dk1 * thom);
        float den = dk * th2 + 2.f * dk1 * thom + dk1 * om2;
        float yv = chk + num / den;
        float dn = dk1 * th2 + 2.f * dk * thom + dk * om2;
        float ld = 2.f * __logf(dn) - 2.f * __logf(den) + __logf(hk) - __logf(wk);

        xs[r][ch * 16 + f] = inside ? yv : xv;   // y in-place (own slot)
        ldacc[j] += inside ? ld : 0.f;
      }
    }
  }

  // ---- ldet: butterfly reduce over the 16 f-lanes (same wave) ----
#pragma unroll
  for (int j = 0; j < 2; ++j) {
    float v = ldacc[j];
    v += __shfl_xor(v, 1);
    v += __shfl_xor(v, 2);
    v += __shfl_xor(v, 4);
    v += __shfl_xor(v, 8);
    if (f == 0) ldet[row0 + rgrp * 2 + j] = v;
  }
  __syncthreads();

  // ---- epilogue: coalesced y writes ----
  for (int i = t; i < ROWS * 64; i += NTHR) {
    int r = i >> 6, c = i & 63;
    out[(size_t)(row0 + r) * 64 + c] = xs[r][c];
  }
#undef ISSUE_SLAB
}

}  // namespace

extern "C" void kernel_launch(void* const* d_in, const int* in_sizes, int n_in,
                              void* d_out, int out_size, void* d_ws, size_t ws_size,
                              hipStream_t stream) {
  const float* x = (const float*)d_in[0];
  const float* W1 = (const float*)d_in[1];
  const float* b1 = (const float*)d_in[2];
  const float* W2 = (const float*)d_in[3];
  const float* b2 = (const float*)d_in[4];
  const float* W3 = (const float*)d_in[5];
  const float* b3 = (const float*)d_in[6];
  float* out = (float*)d_out;
  float* ldet = out + (size_t)65536 * 64;
  float* W3p = (float*)d_ws;   // 128*1792*4 = 917504 B

  pack_w3<<<dim3(800), dim3(256), 0, stream>>>(W3, W3p);
  rqs_fused<<<dim3(65536 / ROWS), dim3(NTHR), 0, stream>>>(
      x, W1, b1, W2, b2, W3p, b3, out, ldet);
}

// Round 11
// 402.099 us; speedup vs baseline: 9.4943x; 1.5065x over previous
//
#include <hip/hip_runtime.h>
#include <math.h>

// RationalQuadraticSpline: fused MLP (64->64->128->1600) + RQ spline.
// R10: lane=row, wave=feature-set. Weights are wave-uniform -> s_load into
// SGPRs (scalar pipe, L2-resident W3f), activations in transposed LDS
// ([col][row], pad 65, stride-1 lane reads). 1 ds_read_b32 per 25 FMAs:
// LDS traffic 30 GB -> ~2 GB; VALU does almost pure FMA. fp32 numerics,
// k-ascending fmaf chains (reference-matching, R5 lesson).

namespace {

constexpr int NTHR = 512;
constexpr int ROWS = 64;
constexpr float TBOUND = 3.0f;

// ---- pack W3 [128][1600] -> W3f [64][128][28]: f-major, k-contiguous ----
__global__ __launch_bounds__(256) void pack_w3(const float* __restrict__ W3,
                                               float* __restrict__ W3f) {
  int idx = blockIdx.x * 256 + threadIdx.x;   // 64*128*25 = 204800
  int f = idx / 3200;
  int rem = idx - f * 3200;
  int k = rem / 25;
  int p = rem - k * 25;
  W3f[(size_t)(f * 128 + k) * 28 + p] = W3[(size_t)k * 1600 + f * 25 + p];
}

__global__ __launch_bounds__(NTHR, 2) void rqs_fused(
    const float* __restrict__ x, const float* __restrict__ W1,
    const float* __restrict__ b1, const float* __restrict__ W2,
    const float* __restrict__ b2, const float* __restrict__ W3f,
    const float* __restrict__ b3, float* __restrict__ out,
    float* __restrict__ ldet) {
  __shared__ float xsT[64 * 65];   // [c][r]; y written back in place
  __shared__ float h1T[64 * 65];   // [c1][r]
  __shared__ float h2T[128 * 65];  // [c2][r]
  __shared__ float ldp[8][64];     // per-wave ldet partials

  const int t = threadIdx.x;
  const int lane = t & 63;
  const int wv = __builtin_amdgcn_readfirstlane(t >> 6);  // wave id, SGPR
  const int row0 = blockIdx.x * ROWS;

  // ---- load x -> xsT (coalesced global, conflict-free LDS) ----
  for (int i = t; i < 64 * 64; i += NTHR) {
    int r = i >> 6, c = i & 63;
    xsT[c * 65 + r] = x[(size_t)(row0 + r) * 64 + c];
  }
  __syncthreads();

  // ---- GEMM1: h1 = relu(x @ W1 + b1); wave -> 8 cols, lane -> row ----
  {
    float acc[8];
#pragma unroll
    for (int j = 0; j < 8; ++j) acc[j] = 0.f;
    const float* w1base = W1 + wv * 8;   // uniform
#pragma unroll 4
    for (int k = 0; k < 64; ++k) {
      float xk = xsT[k * 65 + lane];
      const float* wr = w1base + k * 64;  // uniform -> s_load
#pragma unroll
      for (int j = 0; j < 8; ++j) acc[j] = fmaf(xk, wr[j], acc[j]);
    }
    const float* b1p = b1 + wv * 8;
#pragma unroll
    for (int j = 0; j < 8; ++j)
      h1T[(wv * 8 + j) * 65 + lane] = fmaxf(acc[j] + b1p[j], 0.f);
  }
  __syncthreads();

  // ---- GEMM2: h2 = relu(h1 @ W2 + b2); wave -> 16 cols, lane -> row ----
  {
    float acc[16];
#pragma unroll
    for (int j = 0; j < 16; ++j) acc[j] = 0.f;
    const float* w2base = W2 + wv * 16;  // uniform
#pragma unroll 2
    for (int k = 0; k < 64; ++k) {
      float hk = h1T[k * 65 + lane];
      const float* wr = w2base + k * 128;  // uniform -> s_load
#pragma unroll
      for (int j = 0; j < 16; ++j) acc[j] = fmaf(hk, wr[j], acc[j]);
    }
    const float* b2p = b2 + wv * 16;
#pragma unroll
    for (int j = 0; j < 16; ++j)
      h2T[(wv * 16 + j) * 65 + lane] = fmaxf(acc[j] + b2p[j], 0.f);
  }
  __syncthreads();

  // ---- GEMM3 + spline: wave -> features 8w..8w+7 (sequential), lane -> row ----
  float ldacc = 0.f;
#pragma unroll 1
  for (int i = 0; i < 8; ++i) {
    const int f = wv * 8 + i;                       // uniform
    const float* wf = W3f + (size_t)f * (128 * 28); // uniform
    float acc[25];
#pragma unroll
    for (int p = 0; p < 25; ++p) acc[p] = 0.f;
#pragma unroll 2
    for (int k = 0; k < 128; ++k) {
      float hk = h2T[k * 65 + lane];
      const float* wk = wf + k * 28;  // uniform -> s_load (contiguous 112 B)
#pragma unroll
      for (int p = 0; p < 25; ++p) acc[p] = fmaf(hk, wk[p], acc[p]);
    }
    const float* b3p = b3 + f * 25;  // uniform
#pragma unroll
    for (int p = 0; p < 25; ++p) acc[p] += b3p[p];  // params done

    const float xv = xsT[f * 65 + lane];

    // ---- spline in place on acc (R8-validated numerics) ----
    float m = acc[0];
#pragma unroll
    for (int q = 1; q < 8; ++q) m = fmaxf(m, acc[q]);
    float sum = 0.f;
#pragma unroll
    for (int q = 0; q < 8; ++q) { acc[q] = __expf(acc[q] - m); sum += acc[q]; }
    float sc = 5.952f / sum;
#pragma unroll
    for (int q = 0; q < 8; ++q) acc[q] = acc[q] * sc + 0.001f;
    m = acc[8];
#pragma unroll
    for (int q = 1; q < 8; ++q) m = fmaxf(m, acc[8 + q]);
    sum = 0.f;
#pragma unroll
    for (int q = 0; q < 8; ++q) { acc[8 + q] = __expf(acc[8 + q] - m); sum += acc[8 + q]; }
    sc = 5.952f / sum;
#pragma unroll
    for (int q = 0; q < 8; ++q) acc[8 + q] = acc[8 + q] * sc + 0.001f;
#pragma unroll
    for (int q = 0; q < 9; ++q) {
      float v = acc[16 + q];
      acc[16 + q] = fmaxf(v, 0.f) + __logf(1.f + __expf(-fabsf(v))) + 0.001f;
    }

    const bool inside = (xv >= -TBOUND) && (xv <= TBOUND);
    const float xc = fminf(fmaxf(xv, -TBOUND), TBOUND);

    float cw = -TBOUND + acc[0];
    float chh = -TBOUND + acc[8];
    float cwk = -TBOUND, chk = -TBOUND;
    float wk = acc[0], hk2 = acc[8], dk = acc[16], dk1 = acc[17];
#pragma unroll
    for (int q = 1; q < 8; ++q) {
      bool g = (cw <= xc);
      cwk = g ? cw : cwk;
      chk = g ? chh : chk;
      wk = g ? acc[q] : wk;
      hk2 = g ? acc[8 + q] : hk2;
      dk = g ? acc[16 + q] : dk;
      dk1 = g ? acc[17 + q] : dk1;
      cw += acc[q];
      chh += acc[8 + q];
    }

    float th = (xc - cwk) / wk;
    float om = 1.f - th;
    float th2 = th * th, thom = th * om, om2 = om * om;
    float num = hk2 * (dk * th2 + dk1 * thom);
    float den = dk * th2 + 2.f * dk1 * thom + dk1 * om2;
    float yv = chk + num / den;
    float dn = dk1 * th2 + 2.f * dk * thom + dk * om2;
    float ld = 2.f * __logf(dn) - 2.f * __logf(den) + __logf(hk2) - __logf(wk);

    xsT[f * 65 + lane] = inside ? yv : xv;   // y in place (own slot)
    ldacc += inside ? ld : 0.f;
  }

  ldp[wv][lane] = ldacc;
  __syncthreads();

  // ---- ldet: sum the 8 wave-partials per row (wave-ascending = f-ascending) ----
  if (t < 64) {
    float s2 = 0.f;
#pragma unroll
    for (int w = 0; w < 8; ++w) s2 += ldp[w][t];
    ldet[row0 + t] = s2;
  }

  // ---- epilogue: coalesced y writes ----
  for (int i = t; i < 64 * 64; i += NTHR) {
    int r = i >> 6, c = i & 63;
    out[(size_t)(row0 + r) * 64 + c] = xsT[c * 65 + r];
  }
}

}  // namespace

extern "C" void kernel_launch(void* const* d_in, const int* in_sizes, int n_in,
                              void* d_out, int out_size, void* d_ws, size_t ws_size,
                              hipStream_t stream) {
  const float* x = (const float*)d_in[0];
  const float* W1 = (const float*)d_in[1];
  const float* b1 = (const float*)d_in[2];
  const float* W2 = (const float*)d_in[3];
  const float* b2 = (const float*)d_in[4];
  const float* W3 = (const float*)d_in[5];
  const float* b3 = (const float*)d_in[6];
  float* out = (float*)d_out;
  float* ldet = out + (size_t)65536 * 64;
  float* W3f = (float*)d_ws;   // 64*128*28*4 = 917504 B

  pack_w3<<<dim3(800), dim3(256), 0, stream>>>(W3, W3f);
  rqs_fused<<<dim3(65536 / ROWS), dim3(NTHR), 0, stream>>>(
      x, W1, b1, W2, b2, W3f, b3, out, ldet);
}

// Round 12
// 398.229 us; speedup vs baseline: 9.5866x; 1.0097x over previous
//
#include <hip/hip_runtime.h>
#include <math.h>

// RationalQuadraticSpline: fused MLP (64->64->128->1600) + RQ spline.
// R11: R10 (lane=row, wave-uniform weights via s_load, transposed LDS) plus:
//  - packed fp32 FMA (v_pk_fma_f32) via ext_vector(2) float arithmetic:
//    per-element IEEE fma, same ascending-k chain -> bitwise-same params
//  - h2 computed into registers, written over h1's LDS buffer after barrier:
//    LDS 68.6 -> 50.8 KB -> 3 blocks/CU (launch_bounds(512,3)) = 6 waves/SIMD

namespace {

constexpr int NTHR = 512;
constexpr int ROWS = 64;
constexpr float TBOUND = 3.0f;

typedef __attribute__((ext_vector_type(2))) float f32x2;

// ---- pack W3 [128][1600] -> W3f [64][128][28]: f-major, k-contiguous ----
__global__ __launch_bounds__(256) void pack_w3(const float* __restrict__ W3,
                                               float* __restrict__ W3f) {
  int idx = blockIdx.x * 256 + threadIdx.x;   // 64*128*25 = 204800
  int f = idx / 3200;
  int rem = idx - f * 3200;
  int k = rem / 25;
  int p = rem - k * 25;
  W3f[(size_t)(f * 128 + k) * 28 + p] = W3[(size_t)k * 1600 + f * 25 + p];
}

__global__ __launch_bounds__(NTHR, 3) void rqs_fused(
    const float* __restrict__ x, const float* __restrict__ W1,
    const float* __restrict__ b1, const float* __restrict__ W2,
    const float* __restrict__ b2, const float* __restrict__ W3f,
    const float* __restrict__ b3, float* __restrict__ out,
    float* __restrict__ ldet) {
  __shared__ float xsT[64 * 65];   // [c][r]; y written back in place
  __shared__ float buf[128 * 65];  // h1T ([64][65], first half) then h2T ([128][65])
  __shared__ float ldp[8 * 64];    // per-wave ldet partials

  const int t = threadIdx.x;
  const int lane = t & 63;
  const int wv = __builtin_amdgcn_readfirstlane(t >> 6);  // wave id, SGPR
  const int row0 = blockIdx.x * ROWS;

  // ---- load x -> xsT (coalesced global, conflict-free LDS) ----
  for (int i = t; i < 64 * 64; i += NTHR) {
    int r = i >> 6, c = i & 63;
    xsT[c * 65 + r] = x[(size_t)(row0 + r) * 64 + c];
  }
  __syncthreads();

  // ---- GEMM1: h1 = relu(x @ W1 + b1); wave -> 8 cols, lane -> row ----
  {
    f32x2 acc[4];
#pragma unroll
    for (int j = 0; j < 4; ++j) acc[j] = (f32x2){0.f, 0.f};
    const float* w1base = W1 + wv * 8;   // uniform
#pragma unroll 4
    for (int k = 0; k < 64; ++k) {
      float xk = xsT[k * 65 + lane];
      f32x2 xk2 = (f32x2){xk, xk};
      const f32x2* wr = (const f32x2*)(w1base + k * 64);  // uniform -> s_load
#pragma unroll
      for (int j = 0; j < 4; ++j) acc[j] += xk2 * wr[j];
    }
    const float* b1p = b1 + wv * 8;
#pragma unroll
    for (int j = 0; j < 4; ++j) {
      buf[(wv * 8 + 2 * j + 0) * 65 + lane] = fmaxf(acc[j].x + b1p[2 * j + 0], 0.f);
      buf[(wv * 8 + 2 * j + 1) * 65 + lane] = fmaxf(acc[j].y + b1p[2 * j + 1], 0.f);
    }
  }
  __syncthreads();

  // ---- GEMM2: h2 = relu(h1 @ W2 + b2); wave -> 16 cols, lane -> row ----
  // h2 goes to registers; written over h1's buffer after the barrier.
  float h2r[16];
  {
    f32x2 acc[8];
#pragma unroll
    for (int j = 0; j < 8; ++j) acc[j] = (f32x2){0.f, 0.f};
    const float* w2base = W2 + wv * 16;  // uniform
#pragma unroll 2
    for (int k = 0; k < 64; ++k) {
      float hk = buf[k * 65 + lane];
      f32x2 hk2 = (f32x2){hk, hk};
      const f32x2* wr = (const f32x2*)(w2base + k * 128);  // uniform -> s_load
#pragma unroll
      for (int j = 0; j < 8; ++j) acc[j] += hk2 * wr[j];
    }
    const float* b2p = b2 + wv * 16;
#pragma unroll
    for (int j = 0; j < 8; ++j) {
      h2r[2 * j + 0] = fmaxf(acc[j].x + b2p[2 * j + 0], 0.f);
      h2r[2 * j + 1] = fmaxf(acc[j].y + b2p[2 * j + 1], 0.f);
    }
  }
  __syncthreads();   // all h1 reads done; buf becomes h2T [128][65]
#pragma unroll
  for (int j = 0; j < 16; ++j)
    buf[(wv * 16 + j) * 65 + lane] = h2r[j];
  __syncthreads();

  // ---- GEMM3 + spline: wave -> features 8w..8w+7, lane -> row ----
  float ldacc = 0.f;
#pragma unroll 1
  for (int i = 0; i < 8; ++i) {
    const int f = wv * 8 + i;                       // uniform
    const float* wf = W3f + (size_t)f * (128 * 28); // uniform
    f32x2 acc2[12];
#pragma unroll
    for (int p = 0; p < 12; ++p) acc2[p] = (f32x2){0.f, 0.f};
    float acc24 = 0.f;
#pragma unroll 2
    for (int k = 0; k < 128; ++k) {
      float hk = buf[k * 65 + lane];
      f32x2 hk2 = (f32x2){hk, hk};
      const float* wk = wf + k * 28;                // uniform -> s_load
      const f32x2* wk2 = (const f32x2*)wk;
#pragma unroll
      for (int p = 0; p < 12; ++p) acc2[p] += hk2 * wk2[p];
      acc24 = fmaf(hk, wk[24], acc24);
    }
    float acc[25];
#pragma unroll
    for (int p = 0; p < 12; ++p) { acc[2 * p] = acc2[p].x; acc[2 * p + 1] = acc2[p].y; }
    acc[24] = acc24;
    const float* b3p = b3 + f * 25;  // uniform
#pragma unroll
    for (int p = 0; p < 25; ++p) acc[p] += b3p[p];  // params done

    const float xv = xsT[f * 65 + lane];

    // ---- spline in place on acc (R8-validated numerics) ----
    float m = acc[0];
#pragma unroll
    for (int q = 1; q < 8; ++q) m = fmaxf(m, acc[q]);
    float sum = 0.f;
#pragma unroll
    for (int q = 0; q < 8; ++q) { acc[q] = __expf(acc[q] - m); sum += acc[q]; }
    float sc = 5.952f / sum;
#pragma unroll
    for (int q = 0; q < 8; ++q) acc[q] = acc[q] * sc + 0.001f;
    m = acc[8];
#pragma unroll
    for (int q = 1; q < 8; ++q) m = fmaxf(m, acc[8 + q]);
    sum = 0.f;
#pragma unroll
    for (int q = 0; q < 8; ++q) { acc[8 + q] = __expf(acc[8 + q] - m); sum += acc[8 + q]; }
    sc = 5.952f / sum;
#pragma unroll
    for (int q = 0; q < 8; ++q) acc[8 + q] = acc[8 + q] * sc + 0.001f;
#pragma unroll
    for (int q = 0; q < 9; ++q) {
      float v = acc[16 + q];
      acc[16 + q] = fmaxf(v, 0.f) + __logf(1.f + __expf(-fabsf(v))) + 0.001f;
    }

    const bool inside = (xv >= -TBOUND) && (xv <= TBOUND);
    const float xc = fminf(fmaxf(xv, -TBOUND), TBOUND);

    float cw = -TBOUND + acc[0];
    float chh = -TBOUND + acc[8];
    float cwk = -TBOUND, chk = -TBOUND;
    float wk = acc[0], hk2s = acc[8], dk = acc[16], dk1 = acc[17];
#pragma unroll
    for (int q = 1; q < 8; ++q) {
      bool g = (cw <= xc);
      cwk = g ? cw : cwk;
      chk = g ? chh : chk;
      wk = g ? acc[q] : wk;
      hk2s = g ? acc[8 + q] : hk2s;
      dk = g ? acc[16 + q] : dk;
      dk1 = g ? acc[17 + q] : dk1;
      cw += acc[q];
      chh += acc[8 + q];
    }

    float th = (xc - cwk) / wk;
    float om = 1.f - th;
    float th2 = th * th, thom = th * om, om2 = om * om;
    float num = hk2s * (dk * th2 + dk1 * thom);
    float den = dk * th2 + 2.f * dk1 * thom + dk1 * om2;
    float yv = chk + num / den;
    float dn = dk1 * th2 + 2.f * dk * thom + dk * om2;
    float ld = 2.f * __logf(dn) - 2.f * __logf(den) + __logf(hk2s) - __logf(wk);

    xsT[f * 65 + lane] = inside ? yv : xv;   // y in place (own slot)
    ldacc += inside ? ld : 0.f;
  }

  ldp[wv * 64 + lane] = ldacc;
  __syncthreads();

  // ---- ldet: sum 8 wave-partials per row (wave-ascending = f-ascending) ----
  if (t < 64) {
    float s2 = 0.f;
#pragma unroll
    for (int w = 0; w < 8; ++w) s2 += ldp[w * 64 + t];
    ldet[row0 + t] = s2;
  }

  // ---- epilogue: coalesced y writes ----
  for (int i = t; i < 64 * 64; i += NTHR) {
    int r = i >> 6, c = i & 63;
    out[(size_t)(row0 + r) * 64 + c] = xsT[c * 65 + r];
  }
}

}  // namespace

extern "C" void kernel_launch(void* const* d_in, const int* in_sizes, int n_in,
                              void* d_out, int out_size, void* d_ws, size_t ws_size,
                              hipStream_t stream) {
  const float* x = (const float*)d_in[0];
  const float* W1 = (const float*)d_in[1];
  const float* b1 = (const float*)d_in[2];
  const float* W2 = (const float*)d_in[3];
  const float* b2 = (const float*)d_in[4];
  const float* W3 = (const float*)d_in[5];
  const float* b3 = (const float*)d_in[6];
  float* out = (float*)d_out;
  float* ldet = out + (size_t)65536 * 64;
  float* W3f = (float*)d_ws;   // 64*128*28*4 = 917504 B

  pack_w3<<<dim3(800), dim3(256), 0, stream>>>(W3, W3f);
  rqs_fused<<<dim3(65536 / ROWS), dim3(NTHR), 0, stream>>>(
      x, W1, b1, W2, b2, W3f, b3, out, ldet);
}